// Round 2
// baseline (861.649 us; speedup 1.0000x reference)
//
#include <hip/hip_runtime.h>

typedef unsigned int uint;
typedef unsigned short ushort_t;
typedef __bf16 bf16x8 __attribute__((ext_vector_type(8)));
typedef float f32x4 __attribute__((ext_vector_type(4)));

__device__ __forceinline__ int imin(int a, int b){ return a<b?a:b; }
__device__ __forceinline__ int imax(int a, int b){ return a>b?a:b; }

__device__ __forceinline__ ushort_t f2b(float f){
  uint u = __builtin_bit_cast(uint, f);
  u += 0x7FFFu + ((u>>16)&1u);          // round-to-nearest-even
  return (ushort_t)(u>>16);
}
__device__ __forceinline__ float b2f(ushort_t s){
  uint u = ((uint)s)<<16;
  return __builtin_bit_cast(float, u);
}
__device__ __forceinline__ f32x4 fz4(){ f32x4 z; z[0]=0.f; z[1]=0.f; z[2]=0.f; z[3]=0.f; return z; }

// ---------------- GEMM: C[M,N] = A[M,K] @ W[N,K]^T + bias ----------------
// M=4096, N=1024, K=1024. 128x128 tile, BK=32, 256 threads (4 waves, 64x64 each).
// W is always fp32 in global; converted to bf16 during LDS staging (keeps
// workspace at 32 MB total -- no converted-weight buffers).
struct GArg { const void* A; const float* W; const float* bias; void* O; };

template<bool AFP32, bool OBF16>
__global__ __launch_bounds__(256) void gemm_nt(GArg g0, GArg g1, GArg g2)
{
  GArg g = (blockIdx.z==0) ? g0 : ((blockIdx.z==1) ? g1 : g2);
  // LDS rows padded to 40 elems (80 B): 20-dword stride -> uniform bank spread
  __shared__ ushort_t As[128*40];
  __shared__ ushort_t Bs[128*40];
  const int tid  = threadIdx.x;
  const int lane = tid & 63;
  const int w    = tid >> 6;
  const int ml   = lane & 15, quad = lane >> 4;
  const int m0 = blockIdx.y*128, n0 = blockIdx.x*128;
  const int wm = (w>>1)*64, wn = (w&1)*64;

  f32x4 acc[4][4];
  #pragma unroll
  for (int i=0;i<4;i++)
    #pragma unroll
    for (int j=0;j<4;j++) acc[i][j]=fz4();

  for (int kt=0; kt<32; ++kt){
    // ---- stage A and B tiles (128 x 32 bf16 each) ----
    #pragma unroll
    for (int i=0;i<2;i++){
      int s   = tid + i*256;          // 512 slots of 8 elems
      int row = s>>2, c = s&3;
      int kof = kt*32 + c*8;
      if (AFP32){
        const float* ga = (const float*)g.A + (size_t)(m0+row)*1024 + kof;
        float4 v0 = *(const float4*)ga;
        float4 v1 = *(const float4*)(ga+4);
        uint4 pk;
        pk.x = (uint)f2b(v0.x) | ((uint)f2b(v0.y)<<16);
        pk.y = (uint)f2b(v0.z) | ((uint)f2b(v0.w)<<16);
        pk.z = (uint)f2b(v1.x) | ((uint)f2b(v1.y)<<16);
        pk.w = (uint)f2b(v1.z) | ((uint)f2b(v1.w)<<16);
        *(uint4*)&As[row*40 + c*8] = pk;
      } else {
        const ushort_t* ga = (const ushort_t*)g.A + (size_t)(m0+row)*1024 + kof;
        *(uint4*)&As[row*40 + c*8] = *(const uint4*)ga;
      }
      {
        const float* gb = g.W + (size_t)(n0+row)*1024 + kof;
        float4 v0 = *(const float4*)gb;
        float4 v1 = *(const float4*)(gb+4);
        uint4 pk;
        pk.x = (uint)f2b(v0.x) | ((uint)f2b(v0.y)<<16);
        pk.y = (uint)f2b(v0.z) | ((uint)f2b(v0.w)<<16);
        pk.z = (uint)f2b(v1.x) | ((uint)f2b(v1.y)<<16);
        pk.w = (uint)f2b(v1.z) | ((uint)f2b(v1.w)<<16);
        *(uint4*)&Bs[row*40 + c*8] = pk;
      }
    }
    __syncthreads();
    // ---- fragments + 16 MFMAs ----
    bf16x8 af[4], bfr[4];
    #pragma unroll
    for (int t4=0;t4<4;t4++)
      af[t4]  = __builtin_bit_cast(bf16x8, *(const uint4*)&As[(wm + t4*16 + ml)*40 + quad*8]);
    #pragma unroll
    for (int t4=0;t4<4;t4++)
      bfr[t4] = __builtin_bit_cast(bf16x8, *(const uint4*)&Bs[(wn + t4*16 + ml)*40 + quad*8]);
    #pragma unroll
    for (int ti=0;ti<4;ti++)
      #pragma unroll
      for (int tj=0;tj<4;tj++)
        acc[ti][tj] = __builtin_amdgcn_mfma_f32_16x16x32_bf16(af[ti], bfr[tj], acc[ti][tj], 0,0,0);
    __syncthreads();
  }
  // ---- epilogue: C row=(lane>>4)*4+reg, col=lane&15 (m89-verified layout) ----
  #pragma unroll
  for (int tj=0;tj<4;tj++){
    int gcol = n0 + wn + tj*16 + ml;
    float bv = g.bias[gcol];
    #pragma unroll
    for (int ti=0;ti<4;ti++){
      int growb = m0 + wm + ti*16 + quad*4;
      #pragma unroll
      for (int r=0;r<4;r++){
        float val = acc[ti][tj][r] + bv;
        size_t off = (size_t)(growb + r)*1024 + gcol;
        if (OBF16) ((ushort_t*)g.O)[off] = f2b(val);
        else       ((float*)g.O)[off]    = val;
      }
    }
  }
}

// ---------------- sparse attention ----------------
// wg = (b, h, 32 query rows). 128 threads = 2 waves; wave w owns rows 16w..16w+15.
// Slots: 0..255 strided (j=8*slot), 256..351 local (j = i0-32 + slot-256).
#define SW 356
__global__ __launch_bounds__(128) void attn_k(
    const ushort_t* Qb, const ushort_t* Kb, const ushort_t* Vb,
    ushort_t* Ctxb, float* attn_out)
{
  __shared__ float stash[32*SW];   // unnormalized exp(score)
  __shared__ float invl[32];       // 1 / row-sum
  const int lane = threadIdx.x & 63;
  const int w    = threadIdx.x >> 6;
  const int ml   = lane & 15, quad = lane >> 4;
  const int tile = blockIdx.x, h = blockIdx.y, b = blockIdx.z;
  const int i0  = tile*32;
  const int jl0 = i0 - 32;
  const int rb  = 16*w;
  const size_t bh = (size_t)b*2048*1024 + (size_t)h*64;

  // ---- phase 1: scores -> exp -> stash; row-sums ----
  bf16x8 aq0, aq1;
  {
    const ushort_t* qp = Qb + bh + (size_t)(i0 + rb + ml)*1024 + quad*8;
    aq0 = __builtin_bit_cast(bf16x8, *(const uint4*)qp);
    aq1 = __builtin_bit_cast(bf16x8, *(const uint4*)(qp + 32));
  }
  float lsum[4] = {0.f,0.f,0.f,0.f};
  for (int c=0;c<22;c++){
    int j  = (c<16) ? (128*c + 8*ml) : (jl0 + 16*(c-16) + ml);
    int jc = imin(imax(j,0),2047);
    const ushort_t* kp = Kb + bh + (size_t)jc*1024 + quad*8;
    bf16x8 kb0 = __builtin_bit_cast(bf16x8, *(const uint4*)kp);
    bf16x8 kb1 = __builtin_bit_cast(bf16x8, *(const uint4*)(kp + 32));
    f32x4 sc = fz4();
    sc = __builtin_amdgcn_mfma_f32_16x16x32_bf16(aq0, kb0, sc, 0,0,0);
    sc = __builtin_amdgcn_mfma_f32_16x16x32_bf16(aq1, kb1, sc, 0,0,0);
    int slot = 16*c + ml;
    #pragma unroll
    for (int r=0;r<4;r++){
      int rl = rb + quad*4 + r;
      int i  = i0 + rl;
      bool valid = (c<16) ? true :
        ((j>=0) && (j<2048) && ((j&7)!=0) && (j >= i-32) && (j < i+32));
      float e = valid ? __expf(sc[r]*0.125f) : 0.f;   // masked -> exact 0 (matches exp(-1e9))
      lsum[r] += e;
      stash[rl*SW + slot] = e;
    }
  }
  #pragma unroll
  for (int off=1; off<16; off<<=1){
    #pragma unroll
    for (int r=0;r<4;r++) lsum[r] += __shfl_xor(lsum[r], off);
  }
  if (ml==0){
    #pragma unroll
    for (int r=0;r<4;r++) invl[rb + quad*4 + r] = 1.f / lsum[r];
  }
  // No __syncthreads: each wave only ever touches its own 16 rows of stash/invl.

  // ---- phase 2: coalesced dense attn row writes ----
  const size_t arow = ((size_t)(b*16 + h))*2048;
  for (int it=0; it<128; ++it){
    int r     = rb + (it>>3);
    int inner = ((it&7)<<6) + lane;     // 512 float4-groups per row
    int j0    = inner*4;
    float inv  = invl[r];
    float sval = stash[r*SW + (inner>>1)];            // strided slot (used iff inner even)
    int off    = j0 - jl0;                            // local-window offset (mult of 4)
    int offc   = imin(imax(off,0),92);
    const float4 lv = *(const float4*)&stash[r*SW + 256 + offc];
    bool lok = (off>=0) && (off<96);
    float lx = lok ? lv.x : 0.f;
    float ly = lok ? lv.y : 0.f;
    float lz = lok ? lv.z : 0.f;
    float lw = lok ? lv.w : 0.f;
    float4 o;
    o.x = ((inner&1)==0) ? inv*sval : inv*lx;         // j%8==0 -> strided value
    o.y = inv*ly; o.z = inv*lz; o.w = inv*lw;
    *(float4*)&attn_out[(arow + i0 + r)*2048 + j0] = o;
  }

  // ---- phase 3: PV (VALU; lane = head dim, 16 rows per thread) ----
  float ctx[16];
  #pragma unroll
  for (int rr=0;rr<16;rr++) ctx[rr]=0.f;
  for (int gq=0; gq<88; ++gq){
    int s0 = gq*4;
    float v0,v1,v2,v3;
    {
      int s=s0+0; int j=(s<256)?8*s:(jl0+s-256); int jc=imin(imax(j,0),2047);
      v0 = b2f(Vb[bh + (size_t)jc*1024 + lane]);
    }
    {
      int s=s0+1; int j=(s<256)?8*s:(jl0+s-256); int jc=imin(imax(j,0),2047);
      v1 = b2f(Vb[bh + (size_t)jc*1024 + lane]);
    }
    {
      int s=s0+2; int j=(s<256)?8*s:(jl0+s-256); int jc=imin(imax(j,0),2047);
      v2 = b2f(Vb[bh + (size_t)jc*1024 + lane]);
    }
    {
      int s=s0+3; int j=(s<256)?8*s:(jl0+s-256); int jc=imin(imax(j,0),2047);
      v3 = b2f(Vb[bh + (size_t)jc*1024 + lane]);
    }
    #pragma unroll
    for (int rr=0;rr<16;rr++){
      const float4 p = *(const float4*)&stash[(rb+rr)*SW + s0];  // wave-uniform broadcast
      ctx[rr] += p.x*v0 + p.y*v1 + p.z*v2 + p.w*v3;
    }
  }
  #pragma unroll
  for (int rr=0;rr<16;rr++){
    float val = ctx[rr]*invl[rb+rr];
    Ctxb[bh + (size_t)(i0+rb+rr)*1024 + lane] = f2b(val);
  }
}

extern "C" void kernel_launch(void* const* d_in, const int* in_sizes, int n_in,
                              void* d_out, int out_size, void* d_ws, size_t ws_size,
                              hipStream_t stream) {
  (void)in_sizes; (void)n_in; (void)out_size; (void)ws_size;
  const float* query = (const float*)d_in[0];
  const float* key_  = (const float*)d_in[1];
  const float* value = (const float*)d_in[2];
  const float* Wq = (const float*)d_in[3];
  const float* bq = (const float*)d_in[4];
  const float* Wk = (const float*)d_in[5];
  const float* bk = (const float*)d_in[6];
  const float* Wv = (const float*)d_in[7];
  const float* bv = (const float*)d_in[8];
  const float* Wo = (const float*)d_in[9];
  const float* bo = (const float*)d_in[10];

  // Workspace: exactly 32 MB (Qb/Kb/Vb/Ctxb, bf16 4096x1024 each).
  char* ws = (char*)d_ws;
  ushort_t* Qb   = (ushort_t*)(ws);
  ushort_t* Kb   = (ushort_t*)(ws + (size_t)( 8<<20));
  ushort_t* Vb   = (ushort_t*)(ws + (size_t)(16<<20));
  ushort_t* Ctxb = (ushort_t*)(ws + (size_t)(24<<20));

  float* out = (float*)d_out;
  float* attn_out = out + (size_t)4096*1024;

  GArg ga{query, Wq, bq, Qb};
  GArg gb{key_,  Wk, bk, Kb};
  GArg gc{value, Wv, bv, Vb};
  gemm_nt<true,true><<<dim3(8,32,3), 256, 0, stream>>>(ga, gb, gc);

  attn_k<<<dim3(64,16,2), 128, 0, stream>>>(Qb, Kb, Vb, Ctxb, attn_out);

  GArg go{Ctxb, Wo, bo, out};
  gemm_nt<false,false><<<dim3(8,32,1), 256, 0, stream>>>(go, go, go);
}